// Round 2
// baseline (406.044 us; speedup 1.0000x reference)
//
#include <hip/hip_runtime.h>
#include <hip/hip_bf16.h>

#define BSZ 4
#define SEQ 512
#define HID 768
#define VOC 30522
#define NPAD 30720   // 120*256

typedef __attribute__((ext_vector_type(8))) short short8;
typedef __attribute__((ext_vector_type(4))) float f32x4;

typedef const unsigned int __attribute__((address_space(1)))* gptr_t;
typedef unsigned int __attribute__((address_space(3)))* lptr_t;

__device__ __forceinline__ void gload_lds16(const void* g, void* l) {
    __builtin_amdgcn_global_load_lds((gptr_t)g, (lptr_t)l, 16, 0, 0);
}

// ---------------- span scans: fw = cummax, bw = reverse cummin ----------------
__global__ __launch_bounds__(512) void scan_kernel(const int* __restrict__ span,
                                                   int* __restrict__ fw, int* __restrict__ bw) {
    int b = blockIdx.x;
    int j = threadIdx.x;   // 0..511
    __shared__ int sm[SEQ];
    __shared__ int sc[SEQ];
    int m = (span[b * SEQ + j] > -1) ? 1 : 0;
    sm[j] = m;
    __syncthreads();
    int prev = (j > 0) ? sm[j - 1] : 0;
    int nxt  = (j < SEQ - 1) ? sm[j + 1] : 0;
    int cfw = (m && !prev && j > 0) ? (j - 1) : 0;
    int cbw = (m && !nxt && j < SEQ - 1) ? (j + 1) : (SEQ - 1);

    int v = cfw;
    sc[j] = v; __syncthreads();
    for (int off = 1; off < SEQ; off <<= 1) {
        int o = (j >= off) ? sc[j - off] : 0;
        __syncthreads();
        v = max(v, o);
        sc[j] = v; __syncthreads();
    }
    fw[b * SEQ + j] = v;

    v = cbw;
    sc[j] = v; __syncthreads();
    for (int off = 1; off < SEQ; off <<= 1) {
        int o = (j + off < SEQ) ? sc[j + off] : (SEQ - 1);
        __syncthreads();
        v = min(v, o);
        sc[j] = v; __syncthreads();
    }
    bw[b * SEQ + j] = v;
}

// ---------------- build X = [fw_h | bw_h | pe] * mask, bf16 ----------------
__global__ __launch_bounds__(256) void build_x(const float* __restrict__ h,
                                               const int* __restrict__ span,
                                               const float* __restrict__ pe,
                                               const int* __restrict__ fw,
                                               const int* __restrict__ bw,
                                               __hip_bfloat16* __restrict__ X) {
    int r = blockIdx.x;            // 0..2047
    int b = r >> 9, s = r & (SEQ - 1);
    float mf = (span[r] > -1) ? 1.f : 0.f;
    int f = fw[r], w = bw[r];
    const float* hf = h + ((size_t)b * SEQ + f) * HID;
    const float* hb = h + ((size_t)b * SEQ + w) * HID;
    const float* pp = pe + (size_t)s * HID;
    __hip_bfloat16* xr = X + (size_t)r * (3 * HID);
    for (int c = threadIdx.x; c < HID; c += 256) {
        xr[c]            = __float2bfloat16(hf[c] * mf);
        xr[HID + c]      = __float2bfloat16(hb[c] * mf);
        xr[2 * HID + c]  = __float2bfloat16(pp[c] * mf);
    }
}

// ---------------- transpose + f32->bf16: Wt[n][k] = W[k][n] ----------------
__global__ __launch_bounds__(256) void transpose_bf16(const float* __restrict__ W,
                                                      __hip_bfloat16* __restrict__ Wt,
                                                      int K, int N) {
    __shared__ float t[32][33];
    int n0 = blockIdx.x * 32, k0 = blockIdx.y * 32;
    int tx = threadIdx.x, ty = threadIdx.y;  // (32,8)
    #pragma unroll
    for (int i = 0; i < 32; i += 8) {
        int k = k0 + ty + i, n = n0 + tx;
        t[ty + i][tx] = (n < N) ? W[(size_t)k * N + n] : 0.f;
    }
    __syncthreads();
    #pragma unroll
    for (int i = 0; i < 32; i += 8) {
        int n = n0 + ty + i, k = k0 + tx;
        Wt[(size_t)n * K + k] = __float2bfloat16(t[tx][ty + i]);
    }
}

// ---------------- bias + exact gelu + layernorm -> bf16 ----------------
__global__ __launch_bounds__(256) void gelu_ln(const float* __restrict__ Y,
                                               const float* __restrict__ bias,
                                               const float* __restrict__ g,
                                               const float* __restrict__ be,
                                               __hip_bfloat16* __restrict__ out) {
    int r = blockIdx.x;
    const float* y = Y + (size_t)r * HID;
    float z[3];
    float s1 = 0.f, s2 = 0.f;
    #pragma unroll
    for (int i = 0; i < 3; i++) {
        int c = threadIdx.x + i * 256;
        float x = y[c] + bias[c];
        float zz = 0.5f * x * (1.f + erff(x * 0.70710678118654752f));
        z[i] = zz; s1 += zz; s2 += zz * zz;
    }
    #pragma unroll
    for (int off = 32; off; off >>= 1) {
        s1 += __shfl_down(s1, off);
        s2 += __shfl_down(s2, off);
    }
    __shared__ float p1[4], p2[4];
    int w = threadIdx.x >> 6, lane = threadIdx.x & 63;
    if (lane == 0) { p1[w] = s1; p2[w] = s2; }
    __syncthreads();
    s1 = p1[0] + p1[1] + p1[2] + p1[3];
    s2 = p2[0] + p2[1] + p2[2] + p2[3];
    float mu = s1 * (1.f / HID);
    float var = s2 * (1.f / HID) - mu * mu;
    float rs = rsqrtf(var + 1e-12f);
    __hip_bfloat16* o = out + (size_t)r * HID;
    #pragma unroll
    for (int i = 0; i < 3; i++) {
        int c = threadIdx.x + i * 256;
        o[c] = __float2bfloat16((z[i] - mu) * rs * g[c] + be[c]);
    }
}

// ---------------- 128x128 MFMA GEMM (kept for the small GEMMs) ----------------
template<bool BIAS_EDGE>
__global__ __launch_bounds__(256) void gemm_kernel(const __hip_bfloat16* __restrict__ A,
                                                   const __hip_bfloat16* __restrict__ Bt,
                                                   float* __restrict__ C,
                                                   int K, int Nvalid,
                                                   const float* __restrict__ bias, int ldc) {
    __shared__ __hip_bfloat16 As[128 * 64];
    __shared__ __hip_bfloat16 Bs[128 * 64];
    int bx = blockIdx.x;
    int by = blockIdx.y;
    int t = threadIdx.x;
    int lane = t & 63, w = t >> 6;
    int wm = w >> 1, wn = w & 1;

    const __hip_bfloat16* Ab = A + (size_t)(by * 128) * K;
    const __hip_bfloat16* Bb = Bt + (size_t)(bx * 128) * K;

    f32x4 acc[4][4] = {};

    for (int k0 = 0; k0 < K; k0 += 64) {
        #pragma unroll
        for (int i = 0; i < 4; i++) {
            int c = i * 256 + t;
            int row = c >> 3, col = (c & 7) * 8;
            gload_lds16(Ab + (size_t)row * K + k0 + col, (char*)As + c * 16);
            gload_lds16(Bb + (size_t)row * K + k0 + col, (char*)Bs + c * 16);
        }
        __syncthreads();
        #pragma unroll
        for (int kk = 0; kk < 64; kk += 32) {
            short8 a[4], b[4];
            int col = kk + (lane >> 4) * 8;
            #pragma unroll
            for (int mi = 0; mi < 4; mi++) {
                int row = wm * 64 + mi * 16 + (lane & 15);
                a[mi] = *(const short8*)&As[row * 64 + col];
            }
            #pragma unroll
            for (int ni = 0; ni < 4; ni++) {
                int row = wn * 64 + ni * 16 + (lane & 15);
                b[ni] = *(const short8*)&Bs[row * 64 + col];
            }
            #pragma unroll
            for (int mi = 0; mi < 4; mi++)
                #pragma unroll
                for (int ni = 0; ni < 4; ni++)
                    acc[mi][ni] = __builtin_amdgcn_mfma_f32_16x16x32_bf16(a[mi], b[ni], acc[mi][ni], 0, 0, 0);
        }
        __syncthreads();
    }

    int rq = lane >> 4, cl = lane & 15;
    #pragma unroll
    for (int mi = 0; mi < 4; mi++) {
        #pragma unroll
        for (int ni = 0; ni < 4; ni++) {
            int col = bx * 128 + wn * 64 + ni * 16 + cl;
            #pragma unroll
            for (int j = 0; j < 4; j++) {
                int row = by * 128 + wm * 64 + mi * 16 + rq * 4 + j;
                float v = acc[mi][ni][j];
                if (BIAS_EDGE) {
                    if (col < Nvalid) C[(size_t)row * ldc + col] = v + bias[col];
                } else {
                    C[(size_t)row * ldc + col] = v;
                }
            }
        }
    }
}

// ---------------- 256x256 8-phase MFMA GEMM (T1+T2+T3+T4+T5) ----------------
// BM=BN=256, BK=64, 512 threads (8 waves 2x4), dbuf LDS 128KiB.
// LDS buffer b at b*65536: A rows 0..255 at [0,32768), B rows 0..255 at [32768,65536).
// Half-tiles: A0/A1/B0/B1 = 16KiB each. XOR swizzle: byte ^= ((row&7)<<4),
// realized as inverse-swizzled global SOURCE + swizzled ds_read (linear LDS dest).
template<bool BIAS_EDGE>
__global__ __launch_bounds__(512, 2) void gemm256(const __hip_bfloat16* __restrict__ A,
                                                  const __hip_bfloat16* __restrict__ Bt,
                                                  float* __restrict__ C,
                                                  int K, int Nvalid,
                                                  const float* __restrict__ bias,
                                                  int ldc, int mtiles) {
    __shared__ char lds[131072];
    int nwg = gridDim.x;
    int h = blockIdx.x;
    int q = nwg >> 3;                      // nwg % 8 == 0
    int logical = (h & 7) * q + (h >> 3);  // bijective XCD swizzle
    int bm = logical % mtiles;
    int bn = logical / mtiles;

    int tid = threadIdx.x;
    int lane = tid & 63;
    int w = tid >> 6;            // 0..7
    int wr = w >> 2, wc = w & 3; // 2x4 wave grid within a 128x128 quadrant

    // --- staging (write-side) precompute: chunk c = tid and tid+512
    int r0 = tid >> 3;                                   // 0..63
    int swz8 = (((tid & 7) ^ (r0 & 7)) << 3);            // inverse-swizzled bf16 col
    const __hip_bfloat16* Abase = A + (size_t)(bm * 256) * K;
    const __hip_bfloat16* Bbase = Bt + (size_t)(bn * 256) * K;
    size_t arow0 = (size_t)r0 * K + swz8;
    size_t arow1 = arow0 + (size_t)64 * K;
    int ldsw = tid * 16;

    // --- frag read (swizzled) precompute
    int rxor = (lane & 7) << 4;
    int rcol = ((lane >> 4) & 3) * 16;
    int rc0 = (0 + rcol) ^ rxor;       // ks=0 column bytes
    int rc1 = (64 + rcol) ^ rxor;      // ks=1 column bytes
    int aoff = (wr * 64 + (lane & 15)) * 128;           // + qm*16384 + mi*2048
    int boff = 32768 + (wc * 32 + (lane & 15)) * 128;   // + qn*16384 + ni*2048

    f32x4 acc[2][2][4][2] = {};
    int nt = K >> 6;

#define STAGEA(buf, half, kt) do { \
        const __hip_bfloat16* gg = Abase + (size_t)(half) * 128 * K + (size_t)(kt) * 64; \
        char* dd = lds + (buf) * 65536 + (half) * 16384 + ldsw; \
        gload_lds16(gg + arow0, dd); \
        gload_lds16(gg + arow1, dd + 8192); } while (0)
#define STAGEB(buf, half, kt) do { \
        const __hip_bfloat16* gg = Bbase + (size_t)(half) * 128 * K + (size_t)(kt) * 64; \
        char* dd = lds + (buf) * 65536 + 32768 + (half) * 16384 + ldsw; \
        gload_lds16(gg + arow0, dd); \
        gload_lds16(gg + arow1, dd + 8192); } while (0)

#define MFMA_Q(qm, qn, BF) do { \
        _Pragma("unroll") \
        for (int mi = 0; mi < 4; mi++) \
            _Pragma("unroll") \
            for (int ni = 0; ni < 2; ni++) { \
                acc[qm][qn][mi][ni] = __builtin_amdgcn_mfma_f32_16x16x32_bf16(af[mi][0], BF[ni][0], acc[qm][qn][mi][ni], 0, 0, 0); \
                acc[qm][qn][mi][ni] = __builtin_amdgcn_mfma_f32_16x16x32_bf16(af[mi][1], BF[ni][1], acc[qm][qn][mi][ni], 0, 0, 0); \
            } } while (0)

#define BAR() do { __builtin_amdgcn_s_barrier(); __builtin_amdgcn_sched_barrier(0); } while (0)

    // ---- prologue: K-tile 0 -> buf0 (A0,B0,B1,A1), K-tile 1 -> buf1 (A0,B0,B1)
    STAGEA(0, 0, 0); STAGEB(0, 0, 0); STAGEB(0, 1, 0); STAGEA(0, 1, 0);
    if (nt > 1) { STAGEA(1, 0, 1); STAGEB(1, 0, 1); STAGEB(1, 1, 1); }
    asm volatile("s_waitcnt vmcnt(6)" ::: "memory");
    BAR();

    short8 af[4][2], bf0[2][2], bf1[2][2];
    for (int t = 0; t < nt; ++t) {
        int d = (t & 1) * 65536;

        // ---- Phase 1: quadrant (0,0); read A-half0 (8) + B-half0 (4); stage (t+1)A1
        #pragma unroll
        for (int mi = 0; mi < 4; mi++) {
            af[mi][0] = *(const short8*)(lds + d + aoff + mi * 2048 + rc0);
            af[mi][1] = *(const short8*)(lds + d + aoff + mi * 2048 + rc1);
        }
        #pragma unroll
        for (int ni = 0; ni < 2; ni++) {
            bf0[ni][0] = *(const short8*)(lds + d + boff + ni * 2048 + rc0);
            bf0[ni][1] = *(const short8*)(lds + d + boff + ni * 2048 + rc1);
        }
        if (t + 1 < nt) STAGEA((t + 1) & 1, 1, t + 1);
        BAR();
        __builtin_amdgcn_s_setprio(1);
        MFMA_Q(0, 0, bf0);
        __builtin_amdgcn_s_setprio(0);
        BAR();

        // ---- Phase 2: quadrant (0,1); read B-half1 (4); stage (t+2)A0
        #pragma unroll
        for (int ni = 0; ni < 2; ni++) {
            bf1[ni][0] = *(const short8*)(lds + d + boff + 16384 + ni * 2048 + rc0);
            bf1[ni][1] = *(const short8*)(lds + d + boff + 16384 + ni * 2048 + rc1);
        }
        if (t + 2 < nt) STAGEA(t & 1, 0, t + 2);
        BAR();
        __builtin_amdgcn_s_setprio(1);
        MFMA_Q(0, 1, bf1);
        __builtin_amdgcn_s_setprio(0);
        BAR();

        // ---- Phase 3: quadrant (1,1); read A-half1 (8); stage (t+2)B0
        #pragma unroll
        for (int mi = 0; mi < 4; mi++) {
            af[mi][0] = *(const short8*)(lds + d + 16384 + aoff + mi * 2048 + rc0);
            af[mi][1] = *(const short8*)(lds + d + 16384 + aoff + mi * 2048 + rc1);
        }
        if (t + 2 < nt) STAGEB(t & 1, 0, t + 2);
        BAR();
        __builtin_amdgcn_s_setprio(1);
        MFMA_Q(1, 1, bf1);
        __builtin_amdgcn_s_setprio(0);
        BAR();

        // ---- Phase 4: quadrant (1,0); no ds_reads (A1, B0 in regs); stage (t+2)B1
        if (t + 2 < nt) STAGEB(t & 1, 1, t + 2);
        if (t < nt - 2) asm volatile("s_waitcnt vmcnt(6)" ::: "memory");
        else            asm volatile("s_waitcnt vmcnt(0)" ::: "memory");
        BAR();
        __builtin_amdgcn_s_setprio(1);
        MFMA_Q(1, 0, bf0);
        __builtin_amdgcn_s_setprio(0);
        BAR();
    }

    // ---- epilogue: C write (nontemporal for the big streaming output)
    int rq = lane >> 4, cl = lane & 15;
    #pragma unroll
    for (int qm = 0; qm < 2; qm++)
        #pragma unroll
        for (int qn = 0; qn < 2; qn++)
            #pragma unroll
            for (int mi = 0; mi < 4; mi++)
                #pragma unroll
                for (int ni = 0; ni < 2; ni++) {
                    int col = bn * 256 + qn * 128 + wc * 32 + ni * 16 + cl;
                    if (!BIAS_EDGE || col < Nvalid) {
                        float bv = BIAS_EDGE ? bias[col] : 0.f;
                        #pragma unroll
                        for (int j = 0; j < 4; j++) {
                            int row = bm * 256 + qm * 128 + wr * 64 + mi * 16 + rq * 4 + j;
                            float v = acc[qm][qn][mi][ni][j] + bv;
                            if (BIAS_EDGE)
                                __builtin_nontemporal_store(v, &C[(size_t)row * ldc + col]);
                            else
                                C[(size_t)row * ldc + col] = v;
                        }
                    }
                }
#undef STAGEA
#undef STAGEB
#undef MFMA_Q
#undef BAR
}

extern "C" void kernel_launch(void* const* d_in, const int* in_sizes, int n_in,
                              void* d_out, int out_size, void* d_ws, size_t ws_size,
                              hipStream_t stream) {
    const float* hidden = (const float*)d_in[0];
    const int*   span   = (const int*)d_in[1];
    const float* pe     = (const float*)d_in[2];
    const float* W1     = (const float*)d_in[3];
    const float* b1     = (const float*)d_in[4];
    const float* g1     = (const float*)d_in[5];
    const float* be1    = (const float*)d_in[6];
    const float* W2     = (const float*)d_in[7];
    const float* b2     = (const float*)d_in[8];
    const float* g2     = (const float*)d_in[9];
    const float* be2    = (const float*)d_in[10];
    const float* Wdec   = (const float*)d_in[11];
    const float* dbias  = (const float*)d_in[12];
    float* out = (float*)d_out;

    const int M = BSZ * SEQ;  // 2048
    char* ws = (char*)d_ws;
    size_t off = 0;
    int* fw = (int*)(ws + off);                 off += (size_t)M * 4;
    int* bw = (int*)(ws + off);                 off += (size_t)M * 4;
    __hip_bfloat16* Xb   = (__hip_bfloat16*)(ws + off); off += (size_t)M * 3 * HID * 2;
    __hip_bfloat16* W1t  = (__hip_bfloat16*)(ws + off); off += (size_t)HID * 3 * HID * 2;
    __hip_bfloat16* W2t  = (__hip_bfloat16*)(ws + off); off += (size_t)HID * HID * 2;
    __hip_bfloat16* Wdt  = (__hip_bfloat16*)(ws + off); off += (size_t)NPAD * HID * 2;
    float* Y             = (float*)(ws + off);          off += (size_t)M * HID * 4;
    __hip_bfloat16* mid  = (__hip_bfloat16*)(ws + off); off += (size_t)M * HID * 2;
    __hip_bfloat16* pre  = (__hip_bfloat16*)(ws + off); off += (size_t)M * HID * 2;

    // 1. span scans
    scan_kernel<<<BSZ, SEQ, 0, stream>>>(span, fw, bw);
    // 2. gather + mask -> X bf16
    build_x<<<M, 256, 0, stream>>>(hidden, span, pe, fw, bw, Xb);
    // 3. weight transposes (f32 -> bf16, B^T layout)
    transpose_bf16<<<dim3(HID / 32, 3 * HID / 32), dim3(32, 8), 0, stream>>>(W1, W1t, 3 * HID, HID);
    transpose_bf16<<<dim3(HID / 32, HID / 32), dim3(32, 8), 0, stream>>>(W2, W2t, HID, HID);
    transpose_bf16<<<dim3(NPAD / 32, HID / 32), dim3(32, 8), 0, stream>>>(Wdec, Wdt, HID, VOC);
    // 4. GEMM1: X[2048,2304] @ W1 -> Y[2048,768]
    gemm_kernel<false><<<dim3(HID / 128, M / 128), 256, 0, stream>>>(Xb, W1t, Y, 3 * HID, 0, nullptr, HID);
    // 5. bias+gelu+LN -> mid bf16
    gelu_ln<<<M, 256, 0, stream>>>(Y, b1, g1, be1, mid);
    // 6. GEMM2: mid @ W2 -> Y
    gemm_kernel<false><<<dim3(HID / 128, M / 128), 256, 0, stream>>>(mid, W2t, Y, HID, 0, nullptr, HID);
    // 7. bias+gelu+LN -> pre bf16
    gelu_ln<<<M, 256, 0, stream>>>(Y, b2, g2, be2, pre);
    // 8. decoder GEMM: 256^2 8-phase; grid 8*120=960 (M-tile fastest -> B-panel L2 reuse per XCD)
    gemm256<true><<<(M / 256) * (NPAD / 256), 512, 0, stream>>>(pre, Wdt, out, HID, VOC, dbias, VOC, M / 256);
}

// Round 3
// 278.389 us; speedup vs baseline: 1.4586x; 1.4586x over previous
//
#include <hip/hip_runtime.h>
#include <hip/hip_bf16.h>

#define BSZ 4
#define SEQ 512
#define HID 768
#define VOC 30522
#define NPAD 30720   // 120*256

typedef __attribute__((ext_vector_type(8))) short short8;
typedef __attribute__((ext_vector_type(4))) float f32x4;

typedef const unsigned int __attribute__((address_space(1)))* gptr_t;
typedef unsigned int __attribute__((address_space(3)))* lptr_t;

__device__ __forceinline__ void gload_lds16(const void* g, void* l) {
    __builtin_amdgcn_global_load_lds((gptr_t)g, (lptr_t)l, 16, 0, 0);
}

// ---------------- span scans: fw = cummax, bw = reverse cummin ----------------
__global__ __launch_bounds__(512) void scan_kernel(const int* __restrict__ span,
                                                   int* __restrict__ fw, int* __restrict__ bw) {
    int b = blockIdx.x;
    int j = threadIdx.x;   // 0..511
    __shared__ int sm[SEQ];
    __shared__ int sc[SEQ];
    int m = (span[b * SEQ + j] > -1) ? 1 : 0;
    sm[j] = m;
    __syncthreads();
    int prev = (j > 0) ? sm[j - 1] : 0;
    int nxt  = (j < SEQ - 1) ? sm[j + 1] : 0;
    int cfw = (m && !prev && j > 0) ? (j - 1) : 0;
    int cbw = (m && !nxt && j < SEQ - 1) ? (j + 1) : (SEQ - 1);

    int v = cfw;
    sc[j] = v; __syncthreads();
    for (int off = 1; off < SEQ; off <<= 1) {
        int o = (j >= off) ? sc[j - off] : 0;
        __syncthreads();
        v = max(v, o);
        sc[j] = v; __syncthreads();
    }
    fw[b * SEQ + j] = v;

    v = cbw;
    sc[j] = v; __syncthreads();
    for (int off = 1; off < SEQ; off <<= 1) {
        int o = (j + off < SEQ) ? sc[j + off] : (SEQ - 1);
        __syncthreads();
        v = min(v, o);
        sc[j] = v; __syncthreads();
    }
    bw[b * SEQ + j] = v;
}

// ---------------- build X = [fw_h | bw_h | pe] * mask, bf16 ----------------
__global__ __launch_bounds__(256) void build_x(const float* __restrict__ h,
                                               const int* __restrict__ span,
                                               const float* __restrict__ pe,
                                               const int* __restrict__ fw,
                                               const int* __restrict__ bw,
                                               __hip_bfloat16* __restrict__ X) {
    int r = blockIdx.x;            // 0..2047
    int b = r >> 9, s = r & (SEQ - 1);
    float mf = (span[r] > -1) ? 1.f : 0.f;
    int f = fw[r], w = bw[r];
    const float* hf = h + ((size_t)b * SEQ + f) * HID;
    const float* hb = h + ((size_t)b * SEQ + w) * HID;
    const float* pp = pe + (size_t)s * HID;
    __hip_bfloat16* xr = X + (size_t)r * (3 * HID);
    for (int c = threadIdx.x; c < HID; c += 256) {
        xr[c]            = __float2bfloat16(hf[c] * mf);
        xr[HID + c]      = __float2bfloat16(hb[c] * mf);
        xr[2 * HID + c]  = __float2bfloat16(pp[c] * mf);
    }
}

// ---------------- transpose + f32->bf16: Wt[n][k] = W[k][n] ----------------
__global__ __launch_bounds__(256) void transpose_bf16(const float* __restrict__ W,
                                                      __hip_bfloat16* __restrict__ Wt,
                                                      int K, int N) {
    __shared__ float t[32][33];
    int n0 = blockIdx.x * 32, k0 = blockIdx.y * 32;
    int tx = threadIdx.x, ty = threadIdx.y;  // (32,8)
    #pragma unroll
    for (int i = 0; i < 32; i += 8) {
        int k = k0 + ty + i, n = n0 + tx;
        t[ty + i][tx] = (n < N) ? W[(size_t)k * N + n] : 0.f;
    }
    __syncthreads();
    #pragma unroll
    for (int i = 0; i < 32; i += 8) {
        int n = n0 + ty + i, k = k0 + tx;
        Wt[(size_t)n * K + k] = __float2bfloat16(t[tx][ty + i]);
    }
}

// ---------------- bias + exact gelu + layernorm -> bf16 ----------------
__global__ __launch_bounds__(256) void gelu_ln(const float* __restrict__ Y,
                                               const float* __restrict__ bias,
                                               const float* __restrict__ g,
                                               const float* __restrict__ be,
                                               __hip_bfloat16* __restrict__ out) {
    int r = blockIdx.x;
    const float* y = Y + (size_t)r * HID;
    float z[3];
    float s1 = 0.f, s2 = 0.f;
    #pragma unroll
    for (int i = 0; i < 3; i++) {
        int c = threadIdx.x + i * 256;
        float x = y[c] + bias[c];
        float zz = 0.5f * x * (1.f + erff(x * 0.70710678118654752f));
        z[i] = zz; s1 += zz; s2 += zz * zz;
    }
    #pragma unroll
    for (int off = 32; off; off >>= 1) {
        s1 += __shfl_down(s1, off);
        s2 += __shfl_down(s2, off);
    }
    __shared__ float p1[4], p2[4];
    int w = threadIdx.x >> 6, lane = threadIdx.x & 63;
    if (lane == 0) { p1[w] = s1; p2[w] = s2; }
    __syncthreads();
    s1 = p1[0] + p1[1] + p1[2] + p1[3];
    s2 = p2[0] + p2[1] + p2[2] + p2[3];
    float mu = s1 * (1.f / HID);
    float var = s2 * (1.f / HID) - mu * mu;
    float rs = rsqrtf(var + 1e-12f);
    __hip_bfloat16* o = out + (size_t)r * HID;
    #pragma unroll
    for (int i = 0; i < 3; i++) {
        int c = threadIdx.x + i * 256;
        o[c] = __float2bfloat16((z[i] - mu) * rs * g[c] + be[c]);
    }
}

// ---------------- 128x128 MFMA GEMM (kept for the small GEMMs) ----------------
template<bool BIAS_EDGE>
__global__ __launch_bounds__(256) void gemm_kernel(const __hip_bfloat16* __restrict__ A,
                                                   const __hip_bfloat16* __restrict__ Bt,
                                                   float* __restrict__ C,
                                                   int K, int Nvalid,
                                                   const float* __restrict__ bias, int ldc) {
    __shared__ __hip_bfloat16 As[128 * 64];
    __shared__ __hip_bfloat16 Bs[128 * 64];
    int bx = blockIdx.x;
    int by = blockIdx.y;
    int t = threadIdx.x;
    int lane = t & 63, w = t >> 6;
    int wm = w >> 1, wn = w & 1;

    const __hip_bfloat16* Ab = A + (size_t)(by * 128) * K;
    const __hip_bfloat16* Bb = Bt + (size_t)(bx * 128) * K;

    f32x4 acc[4][4] = {};

    for (int k0 = 0; k0 < K; k0 += 64) {
        #pragma unroll
        for (int i = 0; i < 4; i++) {
            int c = i * 256 + t;
            int row = c >> 3, col = (c & 7) * 8;
            gload_lds16(Ab + (size_t)row * K + k0 + col, (char*)As + c * 16);
            gload_lds16(Bb + (size_t)row * K + k0 + col, (char*)Bs + c * 16);
        }
        __syncthreads();
        #pragma unroll
        for (int kk = 0; kk < 64; kk += 32) {
            short8 a[4], b[4];
            int col = kk + (lane >> 4) * 8;
            #pragma unroll
            for (int mi = 0; mi < 4; mi++) {
                int row = wm * 64 + mi * 16 + (lane & 15);
                a[mi] = *(const short8*)&As[row * 64 + col];
            }
            #pragma unroll
            for (int ni = 0; ni < 4; ni++) {
                int row = wn * 64 + ni * 16 + (lane & 15);
                b[ni] = *(const short8*)&Bs[row * 64 + col];
            }
            #pragma unroll
            for (int mi = 0; mi < 4; mi++)
                #pragma unroll
                for (int ni = 0; ni < 4; ni++)
                    acc[mi][ni] = __builtin_amdgcn_mfma_f32_16x16x32_bf16(a[mi], b[ni], acc[mi][ni], 0, 0, 0);
        }
        __syncthreads();
    }

    int rq = lane >> 4, cl = lane & 15;
    #pragma unroll
    for (int mi = 0; mi < 4; mi++) {
        #pragma unroll
        for (int ni = 0; ni < 4; ni++) {
            int col = bx * 128 + wn * 64 + ni * 16 + cl;
            #pragma unroll
            for (int j = 0; j < 4; j++) {
                int row = by * 128 + wm * 64 + mi * 16 + rq * 4 + j;
                float v = acc[mi][ni][j];
                if (BIAS_EDGE) {
                    if (col < Nvalid) C[(size_t)row * ldc + col] = v + bias[col];
                } else {
                    C[(size_t)row * ldc + col] = v;
                }
            }
        }
    }
}

// ---------------- 256x256 8-phase MFMA GEMM (T1+T2+T3+T4+T5) ----------------
// BM=BN=256, BK=64, 512 threads (8 waves 2x4), dbuf LDS 128KiB.
// LDS buffer b at b*65536: A rows 0..255 at [0,32768), B rows 0..255 at [32768,65536).
// Half-tiles: A0/A1/B0/B1 = 16KiB each. XOR swizzle: byte ^= ((row&7)<<4),
// realized as inverse-swizzled global SOURCE + swizzled ds_read (linear LDS dest).
// R2 fix: no sched_barrier(0) (m141 regression), no nontemporal stores (write amp).
template<bool BIAS_EDGE>
__global__ __launch_bounds__(512, 2) void gemm256(const __hip_bfloat16* __restrict__ A,
                                                  const __hip_bfloat16* __restrict__ Bt,
                                                  float* __restrict__ C,
                                                  int K, int Nvalid,
                                                  const float* __restrict__ bias,
                                                  int ldc, int mtiles) {
    __shared__ char lds[131072];
    int nwg = gridDim.x;
    int h = blockIdx.x;
    int q = nwg >> 3;                      // nwg % 8 == 0
    int logical = (h & 7) * q + (h >> 3);  // bijective XCD swizzle
    int bm = logical % mtiles;
    int bn = logical / mtiles;

    int tid = threadIdx.x;
    int lane = tid & 63;
    int w = tid >> 6;            // 0..7
    int wr = w >> 2, wc = w & 3; // 2x4 wave grid within a 128x128 quadrant

    // --- staging (write-side) precompute
    int r0 = tid >> 3;                                   // 0..63
    int swz8 = (((tid & 7) ^ (r0 & 7)) << 3);            // inverse-swizzled bf16 col
    const __hip_bfloat16* Abase = A + (size_t)(bm * 256) * K;
    const __hip_bfloat16* Bbase = Bt + (size_t)(bn * 256) * K;
    size_t arow0 = (size_t)r0 * K + swz8;
    size_t arow1 = arow0 + (size_t)64 * K;
    int ldsw = tid * 16;

    // --- frag read (swizzled) precompute
    int rxor = (lane & 7) << 4;
    int rcol = ((lane >> 4) & 3) * 16;
    int rc0 = (0 + rcol) ^ rxor;       // ks=0 column bytes
    int rc1 = (64 + rcol) ^ rxor;      // ks=1 column bytes
    int aoff = (wr * 64 + (lane & 15)) * 128;           // + qm*16384 + mi*2048
    int boff = 32768 + (wc * 32 + (lane & 15)) * 128;   // + qn*16384 + ni*2048

    f32x4 acc[2][2][4][2] = {};
    int nt = K >> 6;

#define STAGEA(buf, half, kt) do { \
        const __hip_bfloat16* gg = Abase + (size_t)(half) * 128 * K + (size_t)(kt) * 64; \
        char* dd = lds + (buf) * 65536 + (half) * 16384 + ldsw; \
        gload_lds16(gg + arow0, dd); \
        gload_lds16(gg + arow1, dd + 8192); } while (0)
#define STAGEB(buf, half, kt) do { \
        const __hip_bfloat16* gg = Bbase + (size_t)(half) * 128 * K + (size_t)(kt) * 64; \
        char* dd = lds + (buf) * 65536 + 32768 + (half) * 16384 + ldsw; \
        gload_lds16(gg + arow0, dd); \
        gload_lds16(gg + arow1, dd + 8192); } while (0)

#define MFMA_Q(qm, qn, BF) do { \
        _Pragma("unroll") \
        for (int mi = 0; mi < 4; mi++) \
            _Pragma("unroll") \
            for (int ni = 0; ni < 2; ni++) { \
                acc[qm][qn][mi][ni] = __builtin_amdgcn_mfma_f32_16x16x32_bf16(af[mi][0], BF[ni][0], acc[qm][qn][mi][ni], 0, 0, 0); \
                acc[qm][qn][mi][ni] = __builtin_amdgcn_mfma_f32_16x16x32_bf16(af[mi][1], BF[ni][1], acc[qm][qn][mi][ni], 0, 0, 0); \
            } } while (0)

#define BAR() __builtin_amdgcn_s_barrier()

    // ---- prologue: K-tile 0 -> buf0 (A0,B0,B1,A1), K-tile 1 -> buf1 (A0,B0,B1)
    STAGEA(0, 0, 0); STAGEB(0, 0, 0); STAGEB(0, 1, 0); STAGEA(0, 1, 0);
    if (nt > 1) { STAGEA(1, 0, 1); STAGEB(1, 0, 1); STAGEB(1, 1, 1); }
    asm volatile("s_waitcnt vmcnt(6)" ::: "memory");
    BAR();

    short8 af[4][2], bf0[2][2], bf1[2][2];
    for (int t = 0; t < nt; ++t) {
        int d = (t & 1) * 65536;

        // ---- Phase 1: quadrant (0,0); read A-half0 (8) + B-half0 (4); stage (t+1)A1
        #pragma unroll
        for (int mi = 0; mi < 4; mi++) {
            af[mi][0] = *(const short8*)(lds + d + aoff + mi * 2048 + rc0);
            af[mi][1] = *(const short8*)(lds + d + aoff + mi * 2048 + rc1);
        }
        #pragma unroll
        for (int ni = 0; ni < 2; ni++) {
            bf0[ni][0] = *(const short8*)(lds + d + boff + ni * 2048 + rc0);
            bf0[ni][1] = *(const short8*)(lds + d + boff + ni * 2048 + rc1);
        }
        if (t + 1 < nt) STAGEA((t + 1) & 1, 1, t + 1);
        BAR();
        __builtin_amdgcn_s_setprio(1);
        MFMA_Q(0, 0, bf0);
        __builtin_amdgcn_s_setprio(0);
        BAR();

        // ---- Phase 2: quadrant (0,1); read B-half1 (4); stage (t+2)A0
        #pragma unroll
        for (int ni = 0; ni < 2; ni++) {
            bf1[ni][0] = *(const short8*)(lds + d + boff + 16384 + ni * 2048 + rc0);
            bf1[ni][1] = *(const short8*)(lds + d + boff + 16384 + ni * 2048 + rc1);
        }
        if (t + 2 < nt) STAGEA(t & 1, 0, t + 2);
        BAR();
        __builtin_amdgcn_s_setprio(1);
        MFMA_Q(0, 1, bf1);
        __builtin_amdgcn_s_setprio(0);
        BAR();

        // ---- Phase 3: quadrant (1,1); read A-half1 (8); stage (t+2)B0
        #pragma unroll
        for (int mi = 0; mi < 4; mi++) {
            af[mi][0] = *(const short8*)(lds + d + 16384 + aoff + mi * 2048 + rc0);
            af[mi][1] = *(const short8*)(lds + d + 16384 + aoff + mi * 2048 + rc1);
        }
        if (t + 2 < nt) STAGEB(t & 1, 0, t + 2);
        BAR();
        __builtin_amdgcn_s_setprio(1);
        MFMA_Q(1, 1, bf1);
        __builtin_amdgcn_s_setprio(0);
        BAR();

        // ---- Phase 4: quadrant (1,0); no ds_reads (A1, B0 in regs); stage (t+2)B1
        if (t + 2 < nt) STAGEB(t & 1, 1, t + 2);
        if (t < nt - 2) asm volatile("s_waitcnt vmcnt(6)" ::: "memory");
        else            asm volatile("s_waitcnt vmcnt(0)" ::: "memory");
        BAR();
        __builtin_amdgcn_s_setprio(1);
        MFMA_Q(1, 0, bf0);
        __builtin_amdgcn_s_setprio(0);
        BAR();
    }

    // ---- epilogue: plain C write (L2 coalesces 64B quarter-wave chunks)
    int rq = lane >> 4, cl = lane & 15;
    #pragma unroll
    for (int qm = 0; qm < 2; qm++)
        #pragma unroll
        for (int qn = 0; qn < 2; qn++)
            #pragma unroll
            for (int mi = 0; mi < 4; mi++)
                #pragma unroll
                for (int ni = 0; ni < 2; ni++) {
                    int col = bn * 256 + qn * 128 + wc * 32 + ni * 16 + cl;
                    if (!BIAS_EDGE || col < Nvalid) {
                        float bv = BIAS_EDGE ? bias[col] : 0.f;
                        #pragma unroll
                        for (int j = 0; j < 4; j++) {
                            int row = bm * 256 + qm * 128 + wr * 64 + mi * 16 + rq * 4 + j;
                            C[(size_t)row * ldc + col] = acc[qm][qn][mi][ni][j] + bv;
                        }
                    }
                }
#undef STAGEA
#undef STAGEB
#undef MFMA_Q
#undef BAR
}

extern "C" void kernel_launch(void* const* d_in, const int* in_sizes, int n_in,
                              void* d_out, int out_size, void* d_ws, size_t ws_size,
                              hipStream_t stream) {
    const float* hidden = (const float*)d_in[0];
    const int*   span   = (const int*)d_in[1];
    const float* pe     = (const float*)d_in[2];
    const float* W1     = (const float*)d_in[3];
    const float* b1     = (const float*)d_in[4];
    const float* g1     = (const float*)d_in[5];
    const float* be1    = (const float*)d_in[6];
    const float* W2     = (const float*)d_in[7];
    const float* b2     = (const float*)d_in[8];
    const float* g2     = (const float*)d_in[9];
    const float* be2    = (const float*)d_in[10];
    const float* Wdec   = (const float*)d_in[11];
    const float* dbias  = (const float*)d_in[12];
    float* out = (float*)d_out;

    const int M = BSZ * SEQ;  // 2048
    char* ws = (char*)d_ws;
    size_t off = 0;
    int* fw = (int*)(ws + off);                 off += (size_t)M * 4;
    int* bw = (int*)(ws + off);                 off += (size_t)M * 4;
    __hip_bfloat16* Xb   = (__hip_bfloat16*)(ws + off); off += (size_t)M * 3 * HID * 2;
    __hip_bfloat16* W1t  = (__hip_bfloat16*)(ws + off); off += (size_t)HID * 3 * HID * 2;
    __hip_bfloat16* W2t  = (__hip_bfloat16*)(ws + off); off += (size_t)HID * HID * 2;
    __hip_bfloat16* Wdt  = (__hip_bfloat16*)(ws + off); off += (size_t)NPAD * HID * 2;
    float* Y             = (float*)(ws + off);          off += (size_t)M * HID * 4;
    __hip_bfloat16* mid  = (__hip_bfloat16*)(ws + off); off += (size_t)M * HID * 2;
    __hip_bfloat16* pre  = (__hip_bfloat16*)(ws + off); off += (size_t)M * HID * 2;

    // 1. span scans
    scan_kernel<<<BSZ, SEQ, 0, stream>>>(span, fw, bw);
    // 2. gather + mask -> X bf16
    build_x<<<M, 256, 0, stream>>>(hidden, span, pe, fw, bw, Xb);
    // 3. weight transposes (f32 -> bf16, B^T layout)
    transpose_bf16<<<dim3(HID / 32, 3 * HID / 32), dim3(32, 8), 0, stream>>>(W1, W1t, 3 * HID, HID);
    transpose_bf16<<<dim3(HID / 32, HID / 32), dim3(32, 8), 0, stream>>>(W2, W2t, HID, HID);
    transpose_bf16<<<dim3(NPAD / 32, HID / 32), dim3(32, 8), 0, stream>>>(Wdec, Wdt, HID, VOC);
    // 4. GEMM1: X[2048,2304] @ W1 -> Y[2048,768]
    gemm_kernel<false><<<dim3(HID / 128, M / 128), 256, 0, stream>>>(Xb, W1t, Y, 3 * HID, 0, nullptr, HID);
    // 5. bias+gelu+LN -> mid bf16
    gelu_ln<<<M, 256, 0, stream>>>(Y, b1, g1, be1, mid);
    // 6. GEMM2: mid @ W2 -> Y
    gemm_kernel<false><<<dim3(HID / 128, M / 128), 256, 0, stream>>>(mid, W2t, Y, HID, 0, nullptr, HID);
    // 7. bias+gelu+LN -> pre bf16
    gelu_ln<<<M, 256, 0, stream>>>(Y, b2, g2, be2, pre);
    // 8. decoder GEMM: 256^2 8-phase; grid 8*120=960 (M-tile fastest -> B-panel L2 reuse per XCD)
    gemm256<true><<<(M / 256) * (NPAD / 256), 512, 0, stream>>>(pre, Wdt, out, HID, VOC, dbias, VOC, M / 256);
}